// Round 10
// baseline (222.057 us; speedup 1.0000x reference)
//
#include <hip/hip_runtime.h>
#include <hip/hip_bf16.h>
#include <hip/hip_fp16.h>

#define FD 128
#define CBW 256           // coarse bucket width: bucket = dst >> 8
#define NBK 256           // max buckets
#define FKEYS 8192        // fine sort keys: dstlow(8b) x src-chunk(5b)

typedef _Float16 half8 __attribute__((ext_vector_type(8)));
typedef float f32x4 __attribute__((ext_vector_type(4)));

// ---------------- fused: coarse histogram (blocks 0..255) + W->W^T fp16 (blocks 256,257) ----------------
__global__ __launch_bounds__(256) void k_pre(const int* __restrict__ dst,
                                             int* __restrict__ ccnt, int e, int nb,
                                             const float* __restrict__ W1,
                                             const float* __restrict__ W2,
                                             __half* __restrict__ T1,
                                             __half* __restrict__ T2) {
    __shared__ float sw[128 * 129];
    const int t = threadIdx.x;
    if (blockIdx.x < 256) {
        int* lh = (int*)sw;
        if (t < NBK) lh[t] = 0;
        __syncthreads();
        for (int i = blockIdx.x * 256 + t; i < e; i += 256 * 256)
            atomicAdd(&lh[dst[i] >> 8], 1);
        __syncthreads();
        if (t < nb) {
            int c = lh[t];
            if (c) atomicAdd(&ccnt[t], c);
        }
    } else {
        const float* W = (blockIdx.x == 257) ? W2 : W1;
        __half* T = (blockIdx.x == 257) ? T2 : T1;
#pragma unroll
        for (int i = 0; i < 64; i++) {
            int idx = i * 256 + t;
            sw[(idx >> 7) * 129 + (idx & 127)] = W[idx];
        }
        __syncthreads();
#pragma unroll
        for (int i = 0; i < 32; i++) {
            int o = i * 256 + t;
            int c = o >> 6, kp = o & 63;
            float lo = sw[(kp * 2) * 129 + c];
            float hi = sw[(kp * 2 + 1) * 129 + c];
            *(__half2*)&T[c * 128 + kp * 2] = __floats2half2_rn(lo, hi);
        }
    }
}

// ---------------- scan of coarse counts (single block, nb<=1024) ----------------
__global__ void k_cscan(const int* __restrict__ ccnt, int* __restrict__ cbase,
                        int* __restrict__ ccur, int nb, int* __restrict__ rowptr, int n) {
    __shared__ int wsum[16];
    __shared__ int woff[17];
    const int t = threadIdx.x, lane = t & 63, wid = t >> 6;
    int v = (t < nb) ? ccnt[t] : 0;
    int s = v;
#pragma unroll
    for (int off = 1; off < 64; off <<= 1) {
        int u = __shfl_up(s, off, 64);
        if (lane >= off) s += u;
    }
    if (lane == 63) wsum[wid] = s;
    __syncthreads();
    if (wid == 0) {
        int w2 = (lane < 16) ? wsum[lane] : 0;
#pragma unroll
        for (int off = 1; off < 16; off <<= 1) {
            int u = __shfl_up(w2, off, 64);
            if (lane >= off) w2 += u;
        }
        if (lane < 16) woff[lane + 1] = w2;
        if (lane == 0) woff[0] = 0;
    }
    __syncthreads();
    int excl = woff[wid] + (s - v);
    if (t < nb) { cbase[t] = excl; ccur[t] = excl; }
    if (t == 0) { cbase[nb] = woff[16]; rowptr[n] = woff[16]; }
}

// ---------------- fused: coarse scatter (blocks 0..nscat-1) + layer1 GEMM (rest) ----------------
__global__ __launch_bounds__(256) void k_mid(const int* __restrict__ src,
                                             const int* __restrict__ dst,
                                             int* __restrict__ ccur,
                                             int* __restrict__ ebuf,
                                             int e, int nb, int nscat,
                                             const float* __restrict__ X,
                                             const __half* __restrict__ Wt,
                                             const float* __restrict__ a_s,
                                             const float* __restrict__ a_d,
                                             __half* __restrict__ H,
                                             float* __restrict__ as_,
                                             float* __restrict__ ad_, int n) {
    __shared__ int lh[NBK];
    __shared__ int lb[NBK];
    const int t = threadIdx.x;
    if ((int)blockIdx.x < nscat) {
        const int per = (e + nscat - 1) / nscat;
        const int lo = blockIdx.x * per;
        const int hi = min(e, lo + per);
        if (t < NBK) lh[t] = 0;
        __syncthreads();
        for (int i = lo + t; i < hi; i += 256) atomicAdd(&lh[dst[i] >> 8], 1);
        __syncthreads();
        if (t < nb) {
            int c = lh[t];
            lb[t] = c ? atomicAdd(&ccur[t], c) : 0;
        }
        __syncthreads();
        if (t < NBK) lh[t] = 0;
        __syncthreads();
        for (int i = lo + t; i < hi; i += 256) {
            int d = dst[i];
            int bkt = d >> 8;
            int r = atomicAdd(&lh[bkt], 1);
            ebuf[lb[bkt] + r] = (src[i] << 8) | (d & (CBW - 1));
        }
    } else {
        const int bid = blockIdx.x - nscat;
        const int wave = t >> 6, lane = t & 63;
        const int g = lane >> 4, c16 = lane & 15;
        const int row0 = bid * 64 + wave * 16;

        half8 A[4];
        {
            int row = row0 + c16;
            int rc = (row < n) ? row : (n - 1);
            const float* xp = &X[(size_t)rc * 128 + g * 8];
#pragma unroll
            for (int kc = 0; kc < 4; kc++) {
                float4 x0 = *(const float4*)(xp + kc * 32);
                float4 x1 = *(const float4*)(xp + kc * 32 + 4);
                half8 a;
                a[0] = (_Float16)x0.x; a[1] = (_Float16)x0.y;
                a[2] = (_Float16)x0.z; a[3] = (_Float16)x0.w;
                a[4] = (_Float16)x1.x; a[5] = (_Float16)x1.y;
                a[6] = (_Float16)x1.z; a[7] = (_Float16)x1.w;
                A[kc] = a;
            }
        }
        f32x4 acc[8];
#pragma unroll
        for (int ct = 0; ct < 8; ct++) acc[ct] = (f32x4){0.f, 0.f, 0.f, 0.f};
#pragma unroll
        for (int ct = 0; ct < 8; ct++) {
            const __half* wp = &Wt[(ct * 16 + c16) * 128 + g * 8];
#pragma unroll
            for (int kc = 0; kc < 4; kc++) {
                half8 b = *(const half8*)(wp + kc * 32);
                acc[ct] = __builtin_amdgcn_mfma_f32_16x16x32_f16(A[kc], b, acc[ct], 0, 0, 0);
            }
        }
        float asv[8], adv[8];
#pragma unroll
        for (int ct = 0; ct < 8; ct++) {
            asv[ct] = a_s[ct * 16 + c16];
            adv[ct] = a_d[ct * 16 + c16];
        }
#pragma unroll
        for (int r = 0; r < 4; r++) {
            const int row = row0 + g * 4 + r;
            float vs = 0.f, vd = 0.f;
#pragma unroll
            for (int ct = 0; ct < 8; ct++) {
                float v = acc[ct][r];
                vs += v * asv[ct];
                vd += v * adv[ct];
                if (row < n) H[(size_t)row * 128 + ct * 16 + c16] = __float2half(v);
            }
#pragma unroll
            for (int off = 8; off; off >>= 1) {
                vs += __shfl_xor(vs, off, 16);
                vd += __shfl_xor(vd, off, 16);
            }
            if (c16 == 0 && row < n) { as_[row] = vs; ad_[row] = vd; }
        }
    }
}

// ---------------- fine counting sort: key = (dstlow<<5 | src>>11) ----------------
// Produces rows grouped by dst AND sorted by src chunk (2048-node granularity)
// => aggr gathers sweep H in ascending order => L2-resident working window.
__global__ __launch_bounds__(256) void k_fine(const int* __restrict__ ebuf,
                                              const int* __restrict__ cbase,
                                              int* __restrict__ rowptr,
                                              int* __restrict__ colidx, int n) {
    const int b = blockIdx.x;
    const int node0 = b * CBW;
    const int nloc = min(CBW, n - node0);
    const int beg = cbase[b], end = cbase[b + 1];
    __shared__ int fh[FKEYS];      // 32 KB
    __shared__ int fo[FKEYS];      // 32 KB
    __shared__ int wt4[4];
    const int t = threadIdx.x, lane = t & 63, wid = t >> 6;
#pragma unroll
    for (int i = 0; i < FKEYS / 256; i++) fh[i * 256 + t] = 0;
    __syncthreads();
    for (int e = beg + t; e < end; e += 256) {
        int v = ebuf[e];                             // (src<<8)|dstlow, < 2^24
        int key = ((v & 255) << 5) | (v >> 19);      // v>>19 == src>>11 (<32)
        atomicAdd(&fh[key], 1);
    }
    __syncthreads();
    {   // block-wide exclusive scan over 8192 entries: 32 serial per thread
        const int base = t * 32;
        int sum = 0;
#pragma unroll
        for (int j = 0; j < 32; j++) sum += fh[base + j];
        int s = sum;
#pragma unroll
        for (int off = 1; off < 64; off <<= 1) {
            int u = __shfl_up(s, off, 64);
            if (lane >= off) s += u;
        }
        if (lane == 63) wt4[wid] = s;
        __syncthreads();
        int wo = 0;
#pragma unroll
        for (int j = 0; j < 4; j++) wo += (j < wid) ? wt4[j] : 0;
        int run = wo + s - sum;
#pragma unroll
        for (int j = 0; j < 32; j++) { fo[base + j] = run; run += fh[base + j]; }
    }
    __syncthreads();
    if (t < nloc) rowptr[node0 + t] = beg + fo[t << 5];
#pragma unroll
    for (int i = 0; i < FKEYS / 256; i++) fh[i * 256 + t] = 0;
    __syncthreads();
    for (int e = beg + t; e < end; e += 256) {
        int v = ebuf[e];
        int key = ((v & 255) << 5) | (v >> 19);
        int r = atomicAdd(&fh[key], 1);
        colidx[beg + fo[key] + r] = v >> 8;
    }
}

// ---------------- MFMA GEMM (fp16 input) + fused dots ----------------
__global__ __launch_bounds__(256) void k_gemm(const __half* __restrict__ X,
                                              const __half* __restrict__ Wt,
                                              const float* __restrict__ a_s,
                                              const float* __restrict__ a_d,
                                              __half* __restrict__ H,
                                              float* __restrict__ as_,
                                              float* __restrict__ ad_, int n) {
    const int t = threadIdx.x;
    const int wave = t >> 6, lane = t & 63;
    const int g = lane >> 4, c16 = lane & 15;
    const int row0 = blockIdx.x * 64 + wave * 16;

    half8 A[4];
    {
        int row = row0 + c16;
        int rc = (row < n) ? row : (n - 1);
        const __half* xp = &X[(size_t)rc * 128 + g * 8];
#pragma unroll
        for (int kc = 0; kc < 4; kc++) A[kc] = *(const half8*)(xp + kc * 32);
    }
    f32x4 acc[8];
#pragma unroll
    for (int ct = 0; ct < 8; ct++) acc[ct] = (f32x4){0.f, 0.f, 0.f, 0.f};
#pragma unroll
    for (int ct = 0; ct < 8; ct++) {
        const __half* wp = &Wt[(ct * 16 + c16) * 128 + g * 8];
#pragma unroll
        for (int kc = 0; kc < 4; kc++) {
            half8 b = *(const half8*)(wp + kc * 32);
            acc[ct] = __builtin_amdgcn_mfma_f32_16x16x32_f16(A[kc], b, acc[ct], 0, 0, 0);
        }
    }
    float asv[8], adv[8];
#pragma unroll
    for (int ct = 0; ct < 8; ct++) {
        asv[ct] = a_s[ct * 16 + c16];
        adv[ct] = a_d[ct * 16 + c16];
    }
#pragma unroll
    for (int r = 0; r < 4; r++) {
        const int row = row0 + g * 4 + r;
        float vs = 0.f, vd = 0.f;
#pragma unroll
        for (int ct = 0; ct < 8; ct++) {
            float v = acc[ct][r];
            vs += v * asv[ct];
            vd += v * adv[ct];
            if (row < n) H[(size_t)row * 128 + ct * 16 + c16] = __float2half(v);
        }
#pragma unroll
        for (int off = 8; off; off >>= 1) {
            vs += __shfl_xor(vs, off, 16);
            vd += __shfl_xor(vd, off, 16);
        }
        if (c16 == 0 && row < n) { as_[row] = vs; ad_[row] = vd; }
    }
}

// ---------------- fused softmax + aggregation (LDS-routed (off,w) pairs) ----------------
__device__ __forceinline__ void fmix8(float* acc, uint4 hv, float w) {
    union { uint4 u; _Float16 h[8]; } c;
    c.u = hv;
#pragma unroll
    for (int j = 0; j < 8; j++) acc[j] += w * (float)c.h[j];
}

__global__ __launch_bounds__(256) void k_aggr(const __half* __restrict__ H,
                                              const float* __restrict__ as_,
                                              const float* __restrict__ ad_,
                                              const int* __restrict__ rowptr,
                                              const int* __restrict__ colidx,
                                              const float* __restrict__ bias,
                                              float* __restrict__ outf,
                                              __half* __restrict__ outh,
                                              int n, int mode) {   // mode1: relu+fp16 out
    __shared__ int2 pr[4][64];
    const int wid = threadIdx.x >> 6;
    const int lane = threadIdx.x & 63;
    const int node = blockIdx.x * 4 + wid;
    if (node >= n) return;
    const int q = lane >> 4;
    const int boff = (lane & 15) * 16;
    const char* Hb = (const char*)H + boff;
    const float adn = ad_[node];
    float sp = 0.f;
    float acc[8] = {0.f, 0.f, 0.f, 0.f, 0.f, 0.f, 0.f, 0.f};
    const int beg = rowptr[node], end = rowptr[node + 1];

    {   // self loop
        float e = as_[node] + adn;
        e = (e > 0.f) ? e : 0.2f * e;
        const float w = __expf(e);
        if (lane == 63) sp += w;
        if (q == 3) {
            const uint4 hv = *(const uint4*)(Hb + ((unsigned)node << 8));
            fmix8(acc, hv, w);
        }
    }

    for (int it = beg; it < end; it += 64) {
        const int idx = it + lane;
        const bool valid = idx < end;
        const int sl = colidx[valid ? idx : (end - 1)];
        float e = as_[sl] + adn;
        e = (e > 0.f) ? e : 0.2f * e;
        const float w = valid ? __expf(e) : 0.f;
        sp += w;
        pr[wid][lane] = make_int2((int)((unsigned)sl << 8), __float_as_int(w));
        int m = end - it; if (m > 64) m = 64;
        const int iters = (m + 3) >> 2;
        int slot = q;
#pragma unroll 4
        for (int g = 0; g < iters; ++g) {
            const int2 p = pr[wid][slot];
            const float wg = __int_as_float(p.y);
            const uint4 hv = *(const uint4*)(Hb + (unsigned)p.x);
            fmix8(acc, hv, wg);
            slot += 4;
        }
    }

#pragma unroll
    for (int off = 1; off < 64; off <<= 1) sp += __shfl_xor(sp, off);
#pragma unroll
    for (int off = 16; off <= 32; off <<= 1) {
#pragma unroll
        for (int j = 0; j < 8; j++) acc[j] += __shfl_xor(acc[j], off);
    }
    if (q == 0) {
        const int f0 = boff >> 1;
        const float inv = 1.f / sp;
        float o[8];
        const float4 b0 = *(const float4*)&bias[f0];
        const float4 b1 = *(const float4*)&bias[f0 + 4];
        o[0] = acc[0] * inv + b0.x; o[1] = acc[1] * inv + b0.y;
        o[2] = acc[2] * inv + b0.z; o[3] = acc[3] * inv + b0.w;
        o[4] = acc[4] * inv + b1.x; o[5] = acc[5] * inv + b1.y;
        o[6] = acc[6] * inv + b1.z; o[7] = acc[7] * inv + b1.w;
        if (mode == 1) {
#pragma unroll
            for (int j = 0; j < 8; j++) o[j] = fmaxf(o[j], 0.f);
            union { __half2 h2[4]; uint4 u; } pkk;
            pkk.h2[0] = __floats2half2_rn(o[0], o[1]);
            pkk.h2[1] = __floats2half2_rn(o[2], o[3]);
            pkk.h2[2] = __floats2half2_rn(o[4], o[5]);
            pkk.h2[3] = __floats2half2_rn(o[6], o[7]);
            *(uint4*)&outh[(size_t)node * 128 + f0] = pkk.u;
        } else {
            *(float4*)&outf[(size_t)node * 128 + f0] = make_float4(o[0], o[1], o[2], o[3]);
            *(float4*)&outf[(size_t)node * 128 + f0 + 4] = make_float4(o[4], o[5], o[6], o[7]);
        }
    }
}

extern "C" void kernel_launch(void* const* d_in, const int* in_sizes, int n_in,
                              void* d_out, int out_size, void* d_ws, size_t ws_size,
                              hipStream_t stream) {
    const float* x   = (const float*)d_in[0];
    const int*   ei  = (const int*)d_in[1];
    const float* W1  = (const float*)d_in[2];
    const float* a1s = (const float*)d_in[3];
    const float* a1d = (const float*)d_in[4];
    const float* b1  = (const float*)d_in[5];
    const float* W2  = (const float*)d_in[6];
    const float* a2s = (const float*)d_in[7];
    const float* a2d = (const float*)d_in[8];
    const float* b2  = (const float*)d_in[9];
    float* dout = (float*)d_out;

    const int n = in_sizes[0] / FD;          // 50000
    const int E = in_sizes[1] / 2;           // 1600000
    const int* src = ei;
    const int* dst = ei + E;
    const int NB = (n + CBW - 1) / CBW;      // 196 coarse buckets

    // workspace layout
    // buf0 (12.8 MB) time-shared: ebuf (CSR build) -> Y16 (layer1 output)
    char* base = (char*)d_ws;
    __half* buf0  = (__half*)base;                    // n*128 halves
    int*    ebuf  = (int*)base;                       // E ints (6.4 MB), aliases buf0
    __half* H     = (__half*)(base + (size_t)n * FD * sizeof(__half));
    float* as_    = (float*)((char*)H + (size_t)n * FD * sizeof(__half));
    float* ad_    = as_ + n;
    int*   rowptr = (int*)(ad_ + n);         // n+1
    int*   ccnt   = rowptr + (n + 1);        // NB
    int*   cbase  = ccnt + NB;               // NB+1
    int*   ccur   = cbase + NB + 1;          // NB
    int*   colidx = ccur + NB;               // E
    size_t wt_off = (((size_t)((char*)(colidx + E) - base)) + 15) & ~(size_t)15;
    __half* Wt1h  = (__half*)(base + wt_off);         // 32 KB
    __half* Wt2h  = Wt1h + 128 * 128;                  // 32 KB

    const int gemm_grid = (n + 63) / 64;     // 782
    const int node_grid = (n + 3) / 4;       // 12500
    const int SCAT = 256;

    // ---- D0: zero coarse counts ----
    hipMemsetAsync(ccnt, 0, (size_t)NB * sizeof(int), stream);
    // ---- D1: coarse hist || weight transpose ----
    k_pre<<<258, 256, 0, stream>>>(dst, ccnt, E, NB, W1, W2, Wt1h, Wt2h);
    // ---- D2: scan ----
    k_cscan<<<1, 1024, 0, stream>>>(ccnt, cbase, ccur, NB, rowptr, n);
    // ---- D3: coarse scatter || layer-1 GEMM (reads fp32 x) ----
    k_mid<<<SCAT + gemm_grid, 256, 0, stream>>>(src, dst, ccur, ebuf, E, NB, SCAT,
                                                x, Wt1h, a1s, a1d, H, as_, ad_, n);
    // ---- D4: fine sort (src-ordered rows) -> colidx/rowptr ----
    k_fine<<<NB, 256, 0, stream>>>(ebuf, cbase, rowptr, colidx, n);
    // ---- D5: layer-1 aggregate (relu, fp16 out into buf0; ebuf dead) ----
    k_aggr<<<node_grid, 256, 0, stream>>>(H, as_, ad_, rowptr, colidx, b1,
                                          nullptr, buf0, n, 1);
    // ---- D6: layer-2 GEMM (fp16 input) ----
    k_gemm<<<gemm_grid, 256, 0, stream>>>(buf0, Wt2h, a2s, a2d, H, as_, ad_, n);
    // ---- D7: layer-2 aggregate (fp32 out) ----
    k_aggr<<<node_grid, 256, 0, stream>>>(H, as_, ad_, rowptr, colidx, b2,
                                          dout, nullptr, n, 0);
}

// Round 11
// 208.393 us; speedup vs baseline: 1.0656x; 1.0656x over previous
//
#include <hip/hip_runtime.h>
#include <hip/hip_bf16.h>
#include <hip/hip_fp16.h>

#define FD 128
#define CBW 128           // coarse bucket width: bucket = dst >> 7
#define NBK 512           // max buckets (50000/128 = 391)

typedef _Float16 half8 __attribute__((ext_vector_type(8)));
typedef float f32x4 __attribute__((ext_vector_type(4)));

// ---------------- tiny prep: W1,W2 -> W^T fp16 (blocks 0,1); zero ccnt (block 2) ----------------
__global__ __launch_bounds__(256) void k_wz(const float* __restrict__ W1,
                                            const float* __restrict__ W2,
                                            __half* __restrict__ T1,
                                            __half* __restrict__ T2,
                                            int* __restrict__ ccnt, int nb) {
    const int t = threadIdx.x;
    if (blockIdx.x == 2) {
        for (int i = t; i < nb; i += 256) ccnt[i] = 0;
        return;
    }
    __shared__ float sw[128 * 129];
    const float* W = blockIdx.x ? W2 : W1;
    __half* T = blockIdx.x ? T2 : T1;
#pragma unroll
    for (int i = 0; i < 64; i++) {
        int idx = i * 256 + t;
        sw[(idx >> 7) * 129 + (idx & 127)] = W[idx];
    }
    __syncthreads();
#pragma unroll
    for (int i = 0; i < 32; i++) {
        int o = i * 256 + t;
        int c = o >> 6, kp = o & 63;
        float lo = sw[(kp * 2) * 129 + c];
        float hi = sw[(kp * 2 + 1) * 129 + c];
        *(__half2*)&T[c * 128 + kp * 2] = __floats2half2_rn(lo, hi);
    }
}

// ---------------- fat: coarse histogram (blocks 0..255) || layer-1 GEMM (blocks 256+) ----------------
__global__ __launch_bounds__(256) void k_pg(const int* __restrict__ dst,
                                            int* __restrict__ ccnt, int e, int nb,
                                            const float* __restrict__ X,
                                            const __half* __restrict__ Wt,
                                            const float* __restrict__ a_s,
                                            const float* __restrict__ a_d,
                                            __half* __restrict__ H,
                                            float* __restrict__ as_,
                                            float* __restrict__ ad_, int n) {
    __shared__ int lh[NBK];
    const int t = threadIdx.x;
    if (blockIdx.x < 256) {
        for (int i = t; i < NBK; i += 256) lh[i] = 0;
        __syncthreads();
        for (int i = blockIdx.x * 256 + t; i < e; i += 256 * 256)
            atomicAdd(&lh[dst[i] >> 7], 1);
        __syncthreads();
        for (int i = t; i < nb; i += 256) {
            int c = lh[i];
            if (c) atomicAdd(&ccnt[i], c);
        }
    } else {
        const int bid = blockIdx.x - 256;
        const int wave = t >> 6, lane = t & 63;
        const int g = lane >> 4, c16 = lane & 15;
        const int row0 = bid * 64 + wave * 16;

        half8 A[4];
        {
            int row = row0 + c16;
            int rc = (row < n) ? row : (n - 1);
            const float* xp = &X[(size_t)rc * 128 + g * 8];
#pragma unroll
            for (int kc = 0; kc < 4; kc++) {
                float4 x0 = *(const float4*)(xp + kc * 32);
                float4 x1 = *(const float4*)(xp + kc * 32 + 4);
                half8 a;
                a[0] = (_Float16)x0.x; a[1] = (_Float16)x0.y;
                a[2] = (_Float16)x0.z; a[3] = (_Float16)x0.w;
                a[4] = (_Float16)x1.x; a[5] = (_Float16)x1.y;
                a[6] = (_Float16)x1.z; a[7] = (_Float16)x1.w;
                A[kc] = a;
            }
        }
        f32x4 acc[8];
#pragma unroll
        for (int ct = 0; ct < 8; ct++) acc[ct] = (f32x4){0.f, 0.f, 0.f, 0.f};
#pragma unroll
        for (int ct = 0; ct < 8; ct++) {
            const __half* wp = &Wt[(ct * 16 + c16) * 128 + g * 8];
#pragma unroll
            for (int kc = 0; kc < 4; kc++) {
                half8 b = *(const half8*)(wp + kc * 32);
                acc[ct] = __builtin_amdgcn_mfma_f32_16x16x32_f16(A[kc], b, acc[ct], 0, 0, 0);
            }
        }
        float asv[8], adv[8];
#pragma unroll
        for (int ct = 0; ct < 8; ct++) {
            asv[ct] = a_s[ct * 16 + c16];
            adv[ct] = a_d[ct * 16 + c16];
        }
#pragma unroll
        for (int r = 0; r < 4; r++) {
            const int row = row0 + g * 4 + r;
            float vs = 0.f, vd = 0.f;
#pragma unroll
            for (int ct = 0; ct < 8; ct++) {
                float v = acc[ct][r];
                vs += v * asv[ct];
                vd += v * adv[ct];
                if (row < n) H[(size_t)row * 128 + ct * 16 + c16] = __float2half(v);
            }
#pragma unroll
            for (int off = 8; off; off >>= 1) {
                vs += __shfl_xor(vs, off, 16);
                vd += __shfl_xor(vd, off, 16);
            }
            if (c16 == 0 && row < n) { as_[row] = vs; ad_[row] = vd; }
        }
    }
}

// ---------------- scan of coarse counts (single block, nb<=1024) ----------------
__global__ void k_cscan(const int* __restrict__ ccnt, int* __restrict__ cbase,
                        int* __restrict__ ccur, int nb, int* __restrict__ rowptr, int n) {
    __shared__ int wsum[16];
    __shared__ int woff[17];
    const int t = threadIdx.x, lane = t & 63, wid = t >> 6;
    int v = (t < nb) ? ccnt[t] : 0;
    int s = v;
#pragma unroll
    for (int off = 1; off < 64; off <<= 1) {
        int u = __shfl_up(s, off, 64);
        if (lane >= off) s += u;
    }
    if (lane == 63) wsum[wid] = s;
    __syncthreads();
    if (wid == 0) {
        int w2 = (lane < 16) ? wsum[lane] : 0;
#pragma unroll
        for (int off = 1; off < 16; off <<= 1) {
            int u = __shfl_up(w2, off, 64);
            if (lane >= off) w2 += u;
        }
        if (lane < 16) woff[lane + 1] = w2;
        if (lane == 0) woff[0] = 0;
    }
    __syncthreads();
    int excl = woff[wid] + (s - v);
    if (t < nb) { cbase[t] = excl; ccur[t] = excl; }
    if (t == 0) { cbase[nb] = woff[16]; rowptr[n] = woff[16]; }
}

// ---------------- coarse scatter: pack (src<<7 | dst&127) into bucket-major ebuf ----------------
__global__ __launch_bounds__(256) void k_scat(const int* __restrict__ src,
                                              const int* __restrict__ dst,
                                              int* __restrict__ ccur,
                                              int* __restrict__ ebuf,
                                              int e, int nb, int nscat) {
    __shared__ int lh[NBK];
    __shared__ int lb[NBK];
    const int t = threadIdx.x;
    const int per = (e + nscat - 1) / nscat;
    const int lo = blockIdx.x * per;
    const int hi = min(e, lo + per);
    for (int i = t; i < NBK; i += 256) lh[i] = 0;
    __syncthreads();
    for (int i = lo + t; i < hi; i += 256) atomicAdd(&lh[dst[i] >> 7], 1);
    __syncthreads();
    for (int i = t; i < nb; i += 256) {
        int c = lh[i];
        lb[i] = c ? atomicAdd(&ccur[i], c) : 0;
    }
    __syncthreads();
    for (int i = t; i < NBK; i += 256) lh[i] = 0;
    __syncthreads();
    for (int i = lo + t; i < hi; i += 256) {
        int d = dst[i];
        int bkt = d >> 7;
        int r = atomicAdd(&lh[bkt], 1);
        ebuf[lb[bkt] + r] = (src[i] << 7) | (d & (CBW - 1));
    }
}

// ---------------- fine counting sort within each coarse bucket (CBW=128) ----------------
__global__ __launch_bounds__(256) void k_fine(const int* __restrict__ ebuf,
                                              const int* __restrict__ cbase,
                                              int* __restrict__ rowptr,
                                              int* __restrict__ colidx, int n) {
    const int b = blockIdx.x;
    const int node0 = b * CBW;
    const int nloc = min(CBW, n - node0);
    const int beg = cbase[b], end = cbase[b + 1];
    __shared__ int fh[CBW];
    __shared__ int fo[CBW];
    __shared__ int w0tot;
    const int t = threadIdx.x;
    if (t < CBW) fh[t] = 0;
    __syncthreads();
    for (int e = beg + t; e < end; e += 256) atomicAdd(&fh[ebuf[e] & (CBW - 1)], 1);
    __syncthreads();
    int v = 0, s = 0;
    if (t < CBW) {
        v = fh[t];
        s = v;
#pragma unroll
        for (int off = 1; off < 64; off <<= 1) {
            int u = __shfl_up(s, off, 64);
            if ((t & 63) >= off) s += u;
        }
        if (t == 63) w0tot = s;
    }
    __syncthreads();
    if (t < CBW) fo[t] = ((t >= 64) ? w0tot : 0) + s - v;
    __syncthreads();
    if (t < nloc) rowptr[node0 + t] = beg + fo[t];
    if (t < CBW) fh[t] = 0;
    __syncthreads();
    for (int e = beg + t; e < end; e += 256) {
        int rec = ebuf[e];
        int d = rec & (CBW - 1);
        int r = atomicAdd(&fh[d], 1);
        colidx[beg + fo[d] + r] = rec >> 7;
    }
}

// ---------------- MFMA GEMM (fp16 input) + fused dots ----------------
__global__ __launch_bounds__(256) void k_gemm(const __half* __restrict__ X,
                                              const __half* __restrict__ Wt,
                                              const float* __restrict__ a_s,
                                              const float* __restrict__ a_d,
                                              __half* __restrict__ H,
                                              float* __restrict__ as_,
                                              float* __restrict__ ad_, int n) {
    const int t = threadIdx.x;
    const int wave = t >> 6, lane = t & 63;
    const int g = lane >> 4, c16 = lane & 15;
    const int row0 = blockIdx.x * 64 + wave * 16;

    half8 A[4];
    {
        int row = row0 + c16;
        int rc = (row < n) ? row : (n - 1);
        const __half* xp = &X[(size_t)rc * 128 + g * 8];
#pragma unroll
        for (int kc = 0; kc < 4; kc++) A[kc] = *(const half8*)(xp + kc * 32);
    }
    f32x4 acc[8];
#pragma unroll
    for (int ct = 0; ct < 8; ct++) acc[ct] = (f32x4){0.f, 0.f, 0.f, 0.f};
#pragma unroll
    for (int ct = 0; ct < 8; ct++) {
        const __half* wp = &Wt[(ct * 16 + c16) * 128 + g * 8];
#pragma unroll
        for (int kc = 0; kc < 4; kc++) {
            half8 b = *(const half8*)(wp + kc * 32);
            acc[ct] = __builtin_amdgcn_mfma_f32_16x16x32_f16(A[kc], b, acc[ct], 0, 0, 0);
        }
    }
    float asv[8], adv[8];
#pragma unroll
    for (int ct = 0; ct < 8; ct++) {
        asv[ct] = a_s[ct * 16 + c16];
        adv[ct] = a_d[ct * 16 + c16];
    }
#pragma unroll
    for (int r = 0; r < 4; r++) {
        const int row = row0 + g * 4 + r;
        float vs = 0.f, vd = 0.f;
#pragma unroll
        for (int ct = 0; ct < 8; ct++) {
            float v = acc[ct][r];
            vs += v * asv[ct];
            vd += v * adv[ct];
            if (row < n) H[(size_t)row * 128 + ct * 16 + c16] = __float2half(v);
        }
#pragma unroll
        for (int off = 8; off; off >>= 1) {
            vs += __shfl_xor(vs, off, 16);
            vd += __shfl_xor(vd, off, 16);
        }
        if (c16 == 0 && row < n) { as_[row] = vs; ad_[row] = vd; }
    }
}

// ---------------- fused softmax + aggregation (LDS-routed (off,w) pairs) ----------------
__device__ __forceinline__ void fmix8(float* acc, uint4 hv, float w) {
    union { uint4 u; _Float16 h[8]; } c;
    c.u = hv;
#pragma unroll
    for (int j = 0; j < 8; j++) acc[j] += w * (float)c.h[j];
}

__global__ __launch_bounds__(256) void k_aggr(const __half* __restrict__ H,
                                              const float* __restrict__ as_,
                                              const float* __restrict__ ad_,
                                              const int* __restrict__ rowptr,
                                              const int* __restrict__ colidx,
                                              const float* __restrict__ bias,
                                              float* __restrict__ outf,
                                              __half* __restrict__ outh,
                                              int n, int mode) {   // mode1: relu+fp16 out
    __shared__ int2 pr[4][64];
    const int wid = threadIdx.x >> 6;
    const int lane = threadIdx.x & 63;
    const int node = blockIdx.x * 4 + wid;
    if (node >= n) return;
    const int q = lane >> 4;
    const int boff = (lane & 15) * 16;
    const char* Hb = (const char*)H + boff;
    const float adn = ad_[node];
    float sp = 0.f;
    float acc[8] = {0.f, 0.f, 0.f, 0.f, 0.f, 0.f, 0.f, 0.f};
    const int beg = rowptr[node], end = rowptr[node + 1];

    {   // self loop
        float e = as_[node] + adn;
        e = (e > 0.f) ? e : 0.2f * e;
        const float w = __expf(e);
        if (lane == 63) sp += w;
        if (q == 3) {
            const uint4 hv = *(const uint4*)(Hb + ((unsigned)node << 8));
            fmix8(acc, hv, w);
        }
    }

    for (int it = beg; it < end; it += 64) {
        const int idx = it + lane;
        const bool valid = idx < end;
        const int sl = colidx[valid ? idx : (end - 1)];
        float e = as_[sl] + adn;
        e = (e > 0.f) ? e : 0.2f * e;
        const float w = valid ? __expf(e) : 0.f;
        sp += w;
        pr[wid][lane] = make_int2((int)((unsigned)sl << 8), __float_as_int(w));
        int m = end - it; if (m > 64) m = 64;
        const int iters = (m + 3) >> 2;
        int slot = q;
#pragma unroll 4
        for (int g = 0; g < iters; ++g) {
            const int2 p = pr[wid][slot];
            const float wg = __int_as_float(p.y);
            const uint4 hv = *(const uint4*)(Hb + (unsigned)p.x);
            fmix8(acc, hv, wg);
            slot += 4;
        }
    }

#pragma unroll
    for (int off = 1; off < 64; off <<= 1) sp += __shfl_xor(sp, off);
#pragma unroll
    for (int off = 16; off <= 32; off <<= 1) {
#pragma unroll
        for (int j = 0; j < 8; j++) acc[j] += __shfl_xor(acc[j], off);
    }
    if (q == 0) {
        const int f0 = boff >> 1;
        const float inv = 1.f / sp;
        float o[8];
        const float4 b0 = *(const float4*)&bias[f0];
        const float4 b1 = *(const float4*)&bias[f0 + 4];
        o[0] = acc[0] * inv + b0.x; o[1] = acc[1] * inv + b0.y;
        o[2] = acc[2] * inv + b0.z; o[3] = acc[3] * inv + b0.w;
        o[4] = acc[4] * inv + b1.x; o[5] = acc[5] * inv + b1.y;
        o[6] = acc[6] * inv + b1.z; o[7] = acc[7] * inv + b1.w;
        if (mode == 1) {
#pragma unroll
            for (int j = 0; j < 8; j++) o[j] = fmaxf(o[j], 0.f);
            union { __half2 h2[4]; uint4 u; } pkk;
            pkk.h2[0] = __floats2half2_rn(o[0], o[1]);
            pkk.h2[1] = __floats2half2_rn(o[2], o[3]);
            pkk.h2[2] = __floats2half2_rn(o[4], o[5]);
            pkk.h2[3] = __floats2half2_rn(o[6], o[7]);
            *(uint4*)&outh[(size_t)node * 128 + f0] = pkk.u;
        } else {
            *(float4*)&outf[(size_t)node * 128 + f0] = make_float4(o[0], o[1], o[2], o[3]);
            *(float4*)&outf[(size_t)node * 128 + f0 + 4] = make_float4(o[4], o[5], o[6], o[7]);
        }
    }
}

extern "C" void kernel_launch(void* const* d_in, const int* in_sizes, int n_in,
                              void* d_out, int out_size, void* d_ws, size_t ws_size,
                              hipStream_t stream) {
    const float* x   = (const float*)d_in[0];
    const int*   ei  = (const int*)d_in[1];
    const float* W1  = (const float*)d_in[2];
    const float* a1s = (const float*)d_in[3];
    const float* a1d = (const float*)d_in[4];
    const float* b1  = (const float*)d_in[5];
    const float* W2  = (const float*)d_in[6];
    const float* a2s = (const float*)d_in[7];
    const float* a2d = (const float*)d_in[8];
    const float* b2  = (const float*)d_in[9];
    float* dout = (float*)d_out;

    const int n = in_sizes[0] / FD;          // 50000
    const int E = in_sizes[1] / 2;           // 1600000
    const int* src = ei;
    const int* dst = ei + E;
    const int NB = (n + CBW - 1) / CBW;      // 391 coarse buckets

    // workspace layout
    // buf0 (12.8 MB) time-shared: ebuf (CSR build) -> Y16 (layer1 output)
    char* base = (char*)d_ws;
    __half* buf0  = (__half*)base;                    // n*128 halves
    int*    ebuf  = (int*)base;                       // E ints (6.4 MB), aliases buf0
    __half* H     = (__half*)(base + (size_t)n * FD * sizeof(__half));
    float* as_    = (float*)((char*)H + (size_t)n * FD * sizeof(__half));
    float* ad_    = as_ + n;
    int*   rowptr = (int*)(ad_ + n);         // n+1
    int*   ccnt   = rowptr + (n + 1);        // NB
    int*   cbase  = ccnt + NB;               // NB+1
    int*   ccur   = cbase + NB + 1;          // NB
    int*   colidx = ccur + NB;               // E
    size_t wt_off = (((size_t)((char*)(colidx + E) - base)) + 15) & ~(size_t)15;
    __half* Wt1h  = (__half*)(base + wt_off);         // 32 KB
    __half* Wt2h  = Wt1h + 128 * 128;                  // 32 KB

    const int gemm_grid = (n + 63) / 64;     // 782
    const int node_grid = (n + 3) / 4;       // 12500
    const int SCAT = 256;

    // ---- D0: W transposes + zero ccnt (3 tiny blocks) ----
    k_wz<<<3, 256, 0, stream>>>(W1, W2, Wt1h, Wt2h, ccnt, NB);
    // ---- D1: coarse hist || layer-1 GEMM (reads fp32 x, Wt1h) ----
    k_pg<<<256 + gemm_grid, 256, 0, stream>>>(dst, ccnt, E, NB,
                                              x, Wt1h, a1s, a1d, H, as_, ad_, n);
    // ---- D2: scan ----
    k_cscan<<<1, 1024, 0, stream>>>(ccnt, cbase, ccur, NB, rowptr, n);
    // ---- D3: coarse scatter ----
    k_scat<<<SCAT, 256, 0, stream>>>(src, dst, ccur, ebuf, E, NB, SCAT);
    // ---- D4: fine sort -> colidx/rowptr ----
    k_fine<<<NB, 256, 0, stream>>>(ebuf, cbase, rowptr, colidx, n);
    // ---- D5: layer-1 aggregate (relu, fp16 out into buf0; ebuf dead) ----
    k_aggr<<<node_grid, 256, 0, stream>>>(H, as_, ad_, rowptr, colidx, b1,
                                          nullptr, buf0, n, 1);
    // ---- D6: layer-2 GEMM (fp16 input) ----
    k_gemm<<<gemm_grid, 256, 0, stream>>>(buf0, Wt2h, a2s, a2d, H, as_, ad_, n);
    // ---- D7: layer-2 aggregate (fp32 out) ----
    k_aggr<<<node_grid, 256, 0, stream>>>(H, as_, ad_, rowptr, colidx, b2,
                                          dout, nullptr, n, 0);
}